// Round 1
// baseline (2640.036 us; speedup 1.0000x reference)
//
#include <hip/hip_runtime.h>
#include <math.h>

// GTG replicator dynamics, fp32 baseline.
// B=4096 embeddings dim 1024, 100 classes (padded to 128), 30 iterations.
//
// ws layout (floats):
//   ne   [4096][1024]       @ 0            (16.8 MB)
//   A    [4096][4096]       @ 4,194,304    (67.1 MB)
//   X    [4096][128]        @ 20,971,520   ( 2.1 MB)
//   Ypar [8][4096][128]     @ 21,495,808   (16.8 MB)
//   misc (meanacc double, mean float, flag int) @ 25,690,112
// total ~102.8 MB

#define BSZ  4096
#define DIM  1024
#define NC   100
#define NCP  128
#define NLAB 2048
#define TIT  30
#define SKN  8     // split-K chunks for the iteration GEMM

__device__ __forceinline__ float wave_sum(float v) {
#pragma unroll
  for (int off = 32; off > 0; off >>= 1) v += __shfl_xor(v, off, 64);
  return v;
}

// ---- detect label dtype (int32 vs int64 memory layout) + zero mean acc ----
__global__ void k_detect(const int* __restrict__ lab, double* macc, int* flag) {
  __shared__ int bad;
  if (threadIdx.x == 0) bad = 0;
  __syncthreads();
  int my = 0;
  // Only touch first 2048 int32 slots (safe for either dtype).
  for (int i = threadIdx.x; i < 1024; i += 256) {
    int lo = lab[2 * i], hi = lab[2 * i + 1];
    if (hi != 0 || lo < 0 || lo >= NC) my = 1;
  }
  if (my) bad = 1;  // benign race: all writers store 1
  __syncthreads();
  if (threadIdx.x == 0) { *macc = 0.0; *flag = (bad ? 0 : 1); }  // flag=1 -> int64
}

// ---- X0: labelled rows one-hot, unlabelled rows 1/NC (cols >=100 zero) ----
__global__ void k_init_x(const int* __restrict__ lab, const int* __restrict__ flag,
                         float* __restrict__ X) {
  int gid = blockIdx.x * 256 + threadIdx.x;
  if (gid >= BSZ * (NCP / 4)) return;
  int i = gid >> 5, c4 = (gid & 31) << 2;
  float4 v;
  if (i < NLAB) {
    int l = (*flag) ? lab[2 * i] : lab[i];
    v.x = (c4 + 0 == l) ? 1.f : 0.f;
    v.y = (c4 + 1 == l) ? 1.f : 0.f;
    v.z = (c4 + 2 == l) ? 1.f : 0.f;
    v.w = (c4 + 3 == l) ? 1.f : 0.f;
  } else {
    v.x = (c4 + 0 < NC) ? 0.01f : 0.f;
    v.y = (c4 + 1 < NC) ? 0.01f : 0.f;
    v.z = (c4 + 2 < NC) ? 0.01f : 0.f;
    v.w = (c4 + 3 < NC) ? 0.01f : 0.f;
  }
  *(float4*)(X + (size_t)i * NCP + c4) = v;
}

// ---- row-normalize embedding ----
__global__ __launch_bounds__(256) void k_normalize(const float* __restrict__ emb,
                                                   float* __restrict__ ne) {
  int row = blockIdx.x, t = threadIdx.x;
  float4 v = ((const float4*)(emb + (size_t)row * DIM))[t];
  float ss = v.x * v.x + v.y * v.y + v.z * v.z + v.w * v.w;
  ss = wave_sum(ss);
  __shared__ float red[4];
  int lane = t & 63, wid = t >> 6;
  if (lane == 0) red[wid] = ss;
  __syncthreads();
  float tot = red[0] + red[1] + red[2] + red[3];
  float sc = 1.0f / (sqrtf(tot) + 1e-12f);
  float4 o;
  o.x = v.x * sc; o.y = v.y * sc; o.z = v.z * sc; o.w = v.w * sc;
  ((float4*)(ne + (size_t)row * DIM))[t] = o;
}

// ---- A = ne*ne^T (symmetric: only bi<=bj tiles), diag=0, clamp[0,1], mean ----
__global__ __launch_bounds__(256) void k_syrk(const float* __restrict__ ne,
                                              float* __restrict__ A,
                                              double* __restrict__ macc) {
  int p = blockIdx.x;
  int bi = 0, rem = p;
  while (rem >= 32 - bi) { rem -= 32 - bi; bi++; }
  int bj = bi + rem;
  int rb = bi << 7, cb = bj << 7;

  __shared__ float As[16][128];
  __shared__ float Bs[16][128];
  int t = threadIdx.x, tx = t & 15, ty = t >> 4;
  float acc[8][8];
#pragma unroll
  for (int r = 0; r < 8; r++)
#pragma unroll
    for (int c = 0; c < 8; c++) acc[r][c] = 0.f;

  int m = t & 127, kq = (t >> 7) << 3;
  for (int k0 = 0; k0 < DIM; k0 += 16) {
    const float* pa = ne + (size_t)(rb + m) * DIM + k0 + kq;
    const float* pb = ne + (size_t)(cb + m) * DIM + k0 + kq;
    float4 a0 = *(const float4*)pa;
    float4 a1 = *(const float4*)(pa + 4);
    float4 b0 = *(const float4*)pb;
    float4 b1 = *(const float4*)(pb + 4);
    __syncthreads();
    As[kq + 0][m] = a0.x; As[kq + 1][m] = a0.y; As[kq + 2][m] = a0.z; As[kq + 3][m] = a0.w;
    As[kq + 4][m] = a1.x; As[kq + 5][m] = a1.y; As[kq + 6][m] = a1.z; As[kq + 7][m] = a1.w;
    Bs[kq + 0][m] = b0.x; Bs[kq + 1][m] = b0.y; Bs[kq + 2][m] = b0.z; Bs[kq + 3][m] = b0.w;
    Bs[kq + 4][m] = b1.x; Bs[kq + 5][m] = b1.y; Bs[kq + 6][m] = b1.z; Bs[kq + 7][m] = b1.w;
    __syncthreads();
#pragma unroll
    for (int kk = 0; kk < 16; kk++) {
      float4 r0 = *(const float4*)&As[kk][ty * 8];
      float4 r1 = *(const float4*)&As[kk][ty * 8 + 4];
      float4 c0 = *(const float4*)&Bs[kk][tx * 8];
      float4 c1 = *(const float4*)&Bs[kk][tx * 8 + 4];
      float ar[8] = {r0.x, r0.y, r0.z, r0.w, r1.x, r1.y, r1.z, r1.w};
      float bc[8] = {c0.x, c0.y, c0.z, c0.w, c1.x, c1.y, c1.z, c1.w};
#pragma unroll
      for (int r = 0; r < 8; r++)
#pragma unroll
        for (int c = 0; c < 8; c++)
          acc[r][c] = fmaf(ar[r], bc[c], acc[r][c]);
    }
  }

  // epilogue: clamp, zero diag, partial mean sum, symmetric stores
  float lsum = 0.f;
  float vv[8][8];
#pragma unroll
  for (int r = 0; r < 8; r++) {
    int gr = rb + ty * 8 + r;
#pragma unroll
    for (int c = 0; c < 8; c++) {
      int gc = cb + tx * 8 + c;
      float v = acc[r][c];
      v = fminf(fmaxf(v, 0.f), 1.f);
      if (gr == gc) v = 0.f;
      vv[r][c] = v;
      lsum += v;
    }
  }
  if (bi != bj) lsum *= 2.f;
#pragma unroll
  for (int r = 0; r < 8; r++) {
    int gr = rb + ty * 8 + r;
    float4 s0 = make_float4(vv[r][0], vv[r][1], vv[r][2], vv[r][3]);
    float4 s1 = make_float4(vv[r][4], vv[r][5], vv[r][6], vv[r][7]);
    *(float4*)(A + (size_t)gr * BSZ + cb + tx * 8) = s0;
    *(float4*)(A + (size_t)gr * BSZ + cb + tx * 8 + 4) = s1;
  }
  if (bi != bj) {
#pragma unroll
    for (int c = 0; c < 8; c++) {
      int gc = cb + tx * 8 + c;
      float4 s0 = make_float4(vv[0][c], vv[1][c], vv[2][c], vv[3][c]);
      float4 s1 = make_float4(vv[4][c], vv[5][c], vv[6][c], vv[7][c]);
      *(float4*)(A + (size_t)gc * BSZ + rb + ty * 8) = s0;
      *(float4*)(A + (size_t)gc * BSZ + rb + ty * 8 + 4) = s1;
    }
  }
  float bs = wave_sum(lsum);
  __shared__ float red[4];
  int lane = t & 63, wid = t >> 6;
  if (lane == 0) red[wid] = bs;
  __syncthreads();
  if (t == 0) atomicAdd(macc, (double)(red[0] + red[1] + red[2] + red[3]));
}

__global__ void k_meanfin(const double* __restrict__ macc, float* __restrict__ meanf) {
  *meanf = (float)(*macc / (double)((long long)BSZ * BSZ));
}

// ---- Y_partial[sk] = A_thr[rows, kchunk] @ X[kchunk, :].  A symmetric ->
// stage K-tiles from A rows (no transpose). Threshold applied on load. ----
__global__ __launch_bounds__(256) void k_spmm(const float* __restrict__ A,
                                              const float* __restrict__ X,
                                              float* __restrict__ Yp,
                                              const float* __restrict__ meanf) {
  int b = blockIdx.x;
  int rbi = b & 63, sk = b >> 6;
  int rbase = rbi << 6;           // 64 rows per block
  int kbase = sk << 9;            // 512-wide K chunk
  float mean = *meanf;

  __shared__ float As[64][68];    // [k][m], pad 68 to spread write banks
  __shared__ float Xs[64][128];   // [k][c]

  int t = threadIdx.x, tx = t & 31, ty = t >> 5;  // tx: 4 cols, ty: 8 rows
  float acc[8][4];
#pragma unroll
  for (int r = 0; r < 8; r++)
#pragma unroll
    for (int c = 0; c < 4; c++) acc[r][c] = 0.f;

  int skk = t >> 2, cpart = (t & 3) << 4;
  for (int kc = 0; kc < 512; kc += 64) {
    int k0 = kbase + kc;
    // prefetch to regs (overlaps previous tile's compute)
    const float* pa = A + (size_t)(k0 + skk) * BSZ + rbase + cpart;
    float4 av[4];
#pragma unroll
    for (int q = 0; q < 4; q++) av[q] = *(const float4*)(pa + (q << 2));
    float4 xv8[8];
#pragma unroll
    for (int p2 = 0; p2 < 8; p2++) {
      int off = (p2 << 10) + (t << 2);
      xv8[p2] = *(const float4*)(X + (size_t)(k0 + (off >> 7)) * NCP + (off & 127));
    }
    __syncthreads();
#pragma unroll
    for (int q = 0; q < 4; q++) {
      float4 v = av[q];
      v.x = (v.x < mean) ? 0.f : v.x;
      v.y = (v.y < mean) ? 0.f : v.y;
      v.z = (v.z < mean) ? 0.f : v.z;
      v.w = (v.w < mean) ? 0.f : v.w;
      *(float4*)&As[skk][cpart + (q << 2)] = v;
    }
#pragma unroll
    for (int p2 = 0; p2 < 8; p2++) {
      int off = (p2 << 10) + (t << 2);
      *(float4*)&Xs[off >> 7][off & 127] = xv8[p2];
    }
    __syncthreads();
#pragma unroll 8
    for (int kk = 0; kk < 64; kk++) {
      float4 xv = *(const float4*)&Xs[kk][tx << 2];
      float4 a0 = *(const float4*)&As[kk][ty << 3];
      float4 a1 = *(const float4*)&As[kk][(ty << 3) + 4];
      float ar[8] = {a0.x, a0.y, a0.z, a0.w, a1.x, a1.y, a1.z, a1.w};
#pragma unroll
      for (int r = 0; r < 8; r++) {
        acc[r][0] = fmaf(ar[r], xv.x, acc[r][0]);
        acc[r][1] = fmaf(ar[r], xv.y, acc[r][1]);
        acc[r][2] = fmaf(ar[r], xv.z, acc[r][2]);
        acc[r][3] = fmaf(ar[r], xv.w, acc[r][3]);
      }
    }
  }
  float* dst = Yp + (size_t)sk * BSZ * NCP + (size_t)rbase * NCP + (tx << 2);
#pragma unroll
  for (int r = 0; r < 8; r++) {
    float4 o = make_float4(acc[r][0], acc[r][1], acc[r][2], acc[r][3]);
    *(float4*)(dst + (size_t)((ty << 3) + r) * NCP) = o;
  }
}

// ---- per-row: sum split-K partials, num=X*Y, div, entropy, X+=div, outputs ----
__global__ __launch_bounds__(256) void k_epilogue(const float* __restrict__ Yp,
                                                  float* __restrict__ X,
                                                  float* __restrict__ out, int tit) {
  int lane = threadIdx.x & 63, wid = threadIdx.x >> 6;
  int row = (blockIdx.x << 2) + wid;     // one wave per row
  int c0 = lane << 1;                    // 2 cols per lane
  float y0 = 0.f, y1 = 0.f;
#pragma unroll
  for (int sk = 0; sk < SKN; sk++) {
    float2 v = *(const float2*)(Yp + (size_t)sk * BSZ * NCP + (size_t)row * NCP + c0);
    y0 += v.x; y1 += v.y;
  }
  float2 xv = *(float2*)(X + (size_t)row * NCP + c0);
  float n0 = xv.x * y0, n1 = xv.y * y1;
  float s = wave_sum(n0 + n1);
  float inv = 1.0f / (s + 1e-8f);
  float d0 = n0 * inv, d1 = n1 * inv;
  float e = -(d0 * logf(d0 + 1e-20f)) - (d1 * logf(d1 + 1e-20f));
  e = wave_sum(e);
  xv.x += d0; xv.y += d1;
  *(float2*)(X + (size_t)row * NCP + c0) = xv;
  // Xs output layout [B][NC][T]
  if (c0 < NC)     out[((size_t)row * NC + c0) * TIT + tit] = d0;
  if (c0 + 1 < NC) out[((size_t)row * NC + c0 + 1) * TIT + tit] = d1;
  if (lane == 0)   out[(size_t)BSZ * NC * TIT + (size_t)row * TIT + tit] = e;
}

extern "C" void kernel_launch(void* const* d_in, const int* in_sizes, int n_in,
                              void* d_out, int out_size, void* d_ws, size_t ws_size,
                              hipStream_t stream) {
  const float* emb = (const float*)d_in[0];
  const int* lab = (const int*)d_in[1];
  float* out = (float*)d_out;
  float* ws = (float*)d_ws;

  float* ne = ws;
  float* A  = ne + (size_t)BSZ * DIM;
  float* X  = A + (size_t)BSZ * BSZ;
  float* Yp = X + (size_t)BSZ * NCP;
  float* misc = Yp + (size_t)SKN * BSZ * NCP;
  double* macc = (double*)misc;     // 8B-aligned (offset is even float count)
  float* meanf = misc + 2;
  int* flag = (int*)(misc + 3);

  k_detect<<<dim3(1), dim3(256), 0, stream>>>(lab, macc, flag);
  k_init_x<<<dim3((BSZ * (NCP / 4) + 255) / 256), dim3(256), 0, stream>>>(lab, flag, X);
  k_normalize<<<dim3(BSZ), dim3(256), 0, stream>>>(emb, ne);
  k_syrk<<<dim3(528), dim3(256), 0, stream>>>(ne, A, macc);
  k_meanfin<<<dim3(1), dim3(1), 0, stream>>>(macc, meanf);
  for (int t = 0; t < TIT; t++) {
    k_spmm<<<dim3(64 * SKN), dim3(256), 0, stream>>>(A, X, Yp, meanf);
    k_epilogue<<<dim3(BSZ / 4), dim3(256), 0, stream>>>(Yp, X, out, t);
  }
}

// Round 2
// 2141.912 us; speedup vs baseline: 1.2326x; 1.2326x over previous
//
#include <hip/hip_runtime.h>
#include <math.h>

// GTG replicator dynamics. Round 2: iteration GEMM on bf16 MFMA (split-bf16,
// 3 products ~ fp32 precision). A thresholded+split+packed once, reused 30x.
//
// ws layout (floats):
//   region0 @ 0 (16.8 MB): ne [4096][1024] during syrk; afterwards
//     X    [4096][128] f32   @ 0
//     Xth  [128][4096] bf16  @ 524288   (as ushort, 1 MB)
//     Xtl  [128][4096] bf16  @ 786432
//   A    [4096][4096] @ 4194304   fp32 from syrk, then packed (hi16|lo16) in place
//   Yp   [8][4096][128] @ 20971520 (16.8 MB)
//   misc @ 25165824
// total ~100.7 MB (<= round-1's proven 102.8 MB)

#define BSZ  4096
#define DIM  1024
#define NC   100
#define NCP  128
#define NLAB 2048
#define TIT  30
#define SKN  8

typedef short short8 __attribute__((ext_vector_type(8)));
typedef float f32x4 __attribute__((ext_vector_type(4)));

__device__ __forceinline__ float wave_sum(float v) {
#pragma unroll
  for (int off = 32; off > 0; off >>= 1) v += __shfl_xor(v, off, 64);
  return v;
}

__device__ __forceinline__ ushort f2bf(float f) {  // RN float->bf16 bits
  uint u = __float_as_uint(f);
  return (ushort)((u + 0x7fffu + ((u >> 16) & 1u)) >> 16);
}
__device__ __forceinline__ float bf2f(ushort h) {
  return __uint_as_float(((uint)h) << 16);
}

// ---- detect label dtype (int32 vs int64 layout) + zero mean acc ----
__global__ void k_detect(const int* __restrict__ lab, double* macc, int* flag) {
  __shared__ int bad;
  if (threadIdx.x == 0) bad = 0;
  __syncthreads();
  int my = 0;
  for (int i = threadIdx.x; i < 1024; i += 256) {
    int lo = lab[2 * i], hi = lab[2 * i + 1];
    if (hi != 0 || lo < 0 || lo >= NC) my = 1;
  }
  if (my) bad = 1;
  __syncthreads();
  if (threadIdx.x == 0) { *macc = 0.0; *flag = (bad ? 0 : 1); }
}

// ---- X0 ----
__global__ void k_init_x(const int* __restrict__ lab, const int* __restrict__ flag,
                         float* __restrict__ X) {
  int gid = blockIdx.x * 256 + threadIdx.x;
  if (gid >= BSZ * (NCP / 4)) return;
  int i = gid >> 5, c4 = (gid & 31) << 2;
  float4 v;
  if (i < NLAB) {
    int l = (*flag) ? lab[2 * i] : lab[i];
    v.x = (c4 + 0 == l) ? 1.f : 0.f;
    v.y = (c4 + 1 == l) ? 1.f : 0.f;
    v.z = (c4 + 2 == l) ? 1.f : 0.f;
    v.w = (c4 + 3 == l) ? 1.f : 0.f;
  } else {
    v.x = (c4 + 0 < NC) ? 0.01f : 0.f;
    v.y = (c4 + 1 < NC) ? 0.01f : 0.f;
    v.z = (c4 + 2 < NC) ? 0.01f : 0.f;
    v.w = (c4 + 3 < NC) ? 0.01f : 0.f;
  }
  *(float4*)(X + (size_t)i * NCP + c4) = v;
}

// ---- row-normalize embedding ----
__global__ __launch_bounds__(256) void k_normalize(const float* __restrict__ emb,
                                                   float* __restrict__ ne) {
  int row = blockIdx.x, t = threadIdx.x;
  float4 v = ((const float4*)(emb + (size_t)row * DIM))[t];
  float ss = v.x * v.x + v.y * v.y + v.z * v.z + v.w * v.w;
  ss = wave_sum(ss);
  __shared__ float red[4];
  int lane = t & 63, wid = t >> 6;
  if (lane == 0) red[wid] = ss;
  __syncthreads();
  float tot = red[0] + red[1] + red[2] + red[3];
  float sc = 1.0f / (sqrtf(tot) + 1e-12f);
  float4 o;
  o.x = v.x * sc; o.y = v.y * sc; o.z = v.z * sc; o.w = v.w * sc;
  ((float4*)(ne + (size_t)row * DIM))[t] = o;
}

// ---- A = ne*ne^T, diag=0, clamp[0,1], mean accumulation (fp32, unchanged) ----
__global__ __launch_bounds__(256) void k_syrk(const float* __restrict__ ne,
                                              float* __restrict__ A,
                                              double* __restrict__ macc) {
  int p = blockIdx.x;
  int bi = 0, rem = p;
  while (rem >= 32 - bi) { rem -= 32 - bi; bi++; }
  int bj = bi + rem;
  int rb = bi << 7, cb = bj << 7;

  __shared__ float As[16][128];
  __shared__ float Bs[16][128];
  int t = threadIdx.x, tx = t & 15, ty = t >> 4;
  float acc[8][8];
#pragma unroll
  for (int r = 0; r < 8; r++)
#pragma unroll
    for (int c = 0; c < 8; c++) acc[r][c] = 0.f;

  int m = t & 127, kq = (t >> 7) << 3;
  for (int k0 = 0; k0 < DIM; k0 += 16) {
    const float* pa = ne + (size_t)(rb + m) * DIM + k0 + kq;
    const float* pb = ne + (size_t)(cb + m) * DIM + k0 + kq;
    float4 a0 = *(const float4*)pa;
    float4 a1 = *(const float4*)(pa + 4);
    float4 b0 = *(const float4*)pb;
    float4 b1 = *(const float4*)(pb + 4);
    __syncthreads();
    As[kq + 0][m] = a0.x; As[kq + 1][m] = a0.y; As[kq + 2][m] = a0.z; As[kq + 3][m] = a0.w;
    As[kq + 4][m] = a1.x; As[kq + 5][m] = a1.y; As[kq + 6][m] = a1.z; As[kq + 7][m] = a1.w;
    Bs[kq + 0][m] = b0.x; Bs[kq + 1][m] = b0.y; Bs[kq + 2][m] = b0.z; Bs[kq + 3][m] = b0.w;
    Bs[kq + 4][m] = b1.x; Bs[kq + 5][m] = b1.y; Bs[kq + 6][m] = b1.z; Bs[kq + 7][m] = b1.w;
    __syncthreads();
#pragma unroll
    for (int kk = 0; kk < 16; kk++) {
      float4 r0 = *(const float4*)&As[kk][ty * 8];
      float4 r1 = *(const float4*)&As[kk][ty * 8 + 4];
      float4 c0 = *(const float4*)&Bs[kk][tx * 8];
      float4 c1 = *(const float4*)&Bs[kk][tx * 8 + 4];
      float ar[8] = {r0.x, r0.y, r0.z, r0.w, r1.x, r1.y, r1.z, r1.w};
      float bc[8] = {c0.x, c0.y, c0.z, c0.w, c1.x, c1.y, c1.z, c1.w};
#pragma unroll
      for (int r = 0; r < 8; r++)
#pragma unroll
        for (int c = 0; c < 8; c++)
          acc[r][c] = fmaf(ar[r], bc[c], acc[r][c]);
    }
  }

  float lsum = 0.f;
  float vv[8][8];
#pragma unroll
  for (int r = 0; r < 8; r++) {
    int gr = rb + ty * 8 + r;
#pragma unroll
    for (int c = 0; c < 8; c++) {
      int gc = cb + tx * 8 + c;
      float v = acc[r][c];
      v = fminf(fmaxf(v, 0.f), 1.f);
      if (gr == gc) v = 0.f;
      vv[r][c] = v;
      lsum += v;
    }
  }
  if (bi != bj) lsum *= 2.f;
#pragma unroll
  for (int r = 0; r < 8; r++) {
    int gr = rb + ty * 8 + r;
    float4 s0 = make_float4(vv[r][0], vv[r][1], vv[r][2], vv[r][3]);
    float4 s1 = make_float4(vv[r][4], vv[r][5], vv[r][6], vv[r][7]);
    *(float4*)(A + (size_t)gr * BSZ + cb + tx * 8) = s0;
    *(float4*)(A + (size_t)gr * BSZ + cb + tx * 8 + 4) = s1;
  }
  if (bi != bj) {
#pragma unroll
    for (int c = 0; c < 8; c++) {
      int gc = cb + tx * 8 + c;
      float4 s0 = make_float4(vv[0][c], vv[1][c], vv[2][c], vv[3][c]);
      float4 s1 = make_float4(vv[4][c], vv[5][c], vv[6][c], vv[7][c]);
      *(float4*)(A + (size_t)gc * BSZ + rb + ty * 8) = s0;
      *(float4*)(A + (size_t)gc * BSZ + rb + ty * 8 + 4) = s1;
    }
  }
  float bs = wave_sum(lsum);
  __shared__ float red[4];
  int lane = t & 63, wid = t >> 6;
  if (lane == 0) red[wid] = bs;
  __syncthreads();
  if (t == 0) atomicAdd(macc, (double)(red[0] + red[1] + red[2] + red[3]));
}

__global__ void k_meanfin(const double* __restrict__ macc, float* __restrict__ meanf) {
  *meanf = (float)(*macc / (double)((long long)BSZ * BSZ));
}

// ---- threshold + split-bf16 + pack A in place: f32 -> (hi16<<16)|lo16 ----
__global__ __launch_bounds__(256) void k_split_a(float* __restrict__ A,
                                                 const float* __restrict__ meanf) {
  float mean = *meanf;
  int b = blockIdx.x, t = threadIdx.x;
#pragma unroll
  for (int i = 0; i < 8; i++) {
    size_t idx = ((size_t)i * 2048 * 256 + (size_t)b * 256 + t);
    float4 v = *(const float4*)(A + idx * 4);
    uint4 o;
    float f[4] = {v.x, v.y, v.z, v.w};
    uint  r[4];
#pragma unroll
    for (int j = 0; j < 4; j++) {
      float a = (f[j] < mean) ? 0.f : f[j];
      ushort hi = f2bf(a);
      float rest = a - bf2f(hi);
      ushort lo = f2bf(rest);
      r[j] = ((uint)hi << 16) | (uint)lo;
    }
    o.x = r[0]; o.y = r[1]; o.z = r[2]; o.w = r[3];
    *(uint4*)(A + idx * 4) = o;
  }
}

// ---- initial X split+transpose: X f32 [4096][128] -> Xth/Xtl [128][4096] bf16 ----
__global__ __launch_bounds__(256) void k_splitx0(const float* __restrict__ X,
                                                 ushort* __restrict__ Xth,
                                                 ushort* __restrict__ Xtl) {
  __shared__ float xk[64][132];
  int t = threadIdx.x;
  int k0 = blockIdx.x * 64;
#pragma unroll
  for (int p = 0; p < 8; p++) {
    int v = p * 256 + t;
    int krow = v >> 5, q = v & 31;
    float4 f = *(const float4*)(X + (size_t)(k0 + krow) * NCP + q * 4);
    *(float4*)&xk[krow][q * 4] = f;
  }
  __syncthreads();
  int n = t >> 1, half = t & 1;
  ushort hh[32], ll[32];
#pragma unroll
  for (int j = 0; j < 32; j++) {
    float v = xk[half * 32 + j][n];
    ushort hi = f2bf(v);
    hh[j] = hi;
    ll[j] = f2bf(v - bf2f(hi));
  }
  size_t base = (size_t)n * BSZ + k0 + half * 32;
#pragma unroll
  for (int g = 0; g < 4; g++) {
    uint4 oh, ol;
    oh.x = (uint)hh[g*8+0] | ((uint)hh[g*8+1] << 16);
    oh.y = (uint)hh[g*8+2] | ((uint)hh[g*8+3] << 16);
    oh.z = (uint)hh[g*8+4] | ((uint)hh[g*8+5] << 16);
    oh.w = (uint)hh[g*8+6] | ((uint)hh[g*8+7] << 16);
    ol.x = (uint)ll[g*8+0] | ((uint)ll[g*8+1] << 16);
    ol.y = (uint)ll[g*8+2] | ((uint)ll[g*8+3] << 16);
    ol.z = (uint)ll[g*8+4] | ((uint)ll[g*8+5] << 16);
    ol.w = (uint)ll[g*8+6] | ((uint)ll[g*8+7] << 16);
    *(uint4*)(Xth + base + g * 8) = oh;
    *(uint4*)(Xtl + base + g * 8) = ol;
  }
}

// ---- MFMA GEMM: Yp[sk] = Ah@Xh + Ah@Xl + Al@Xh over K-chunk of 512 ----
__global__ __launch_bounds__(512) void k_gemm(const uint* __restrict__ Ap,
                                              const ushort* __restrict__ Xth,
                                              const ushort* __restrict__ Xtl,
                                              float* __restrict__ Yp) {
  __shared__ __align__(16) ushort sAh[128][88];
  __shared__ __align__(16) ushort sAl[128][88];
  __shared__ __align__(16) ushort sXh[128][88];
  __shared__ __align__(16) ushort sXl[128][88];

  int b = blockIdx.x;
  int mt = b & 31, sk = b >> 5;
  int rbase = mt << 7;
  int kchunk = sk << 9;

  int t = threadIdx.x;
  int lane = t & 63, wid = t >> 6;
  int wm = wid >> 2, wn = wid & 3;   // wave tile: 64 rows x 32 cols
  int l15 = lane & 15, l4 = lane >> 4;

  f32x4 acc[4][2];
#pragma unroll
  for (int mi = 0; mi < 4; mi++)
#pragma unroll
    for (int ni = 0; ni < 2; ni++) acc[mi][ni] = (f32x4){0.f, 0.f, 0.f, 0.f};

  for (int kt = 0; kt < 8; kt++) {
    int k0 = kchunk + kt * 64;
    // global -> regs
    uint4 apk[4];
    int arow[4], aq[4];
#pragma unroll
    for (int p = 0; p < 4; p++) {
      int v = p * 512 + t;
      arow[p] = v >> 4; aq[p] = v & 15;
      apk[p] = *(const uint4*)(Ap + (size_t)(rbase + arow[p]) * BSZ + k0 + aq[p] * 4);
    }
    uint4 xh[2], xl[2];
    int xn[2], xs[2];
#pragma unroll
    for (int p = 0; p < 2; p++) {
      int v = p * 512 + t;
      xn[p] = v >> 3; xs[p] = v & 7;
      size_t off = (size_t)xn[p] * BSZ + k0 + xs[p] * 8;
      xh[p] = *(const uint4*)(Xth + off);
      xl[p] = *(const uint4*)(Xtl + off);
    }
    __syncthreads();
    // regs -> LDS (unpack A)
#pragma unroll
    for (int p = 0; p < 4; p++) {
      uint2 wh, wl;
      wh.x = (apk[p].x >> 16) | (apk[p].y & 0xffff0000u);
      wh.y = (apk[p].z >> 16) | (apk[p].w & 0xffff0000u);
      wl.x = (apk[p].x & 0xffffu) | (apk[p].y << 16);
      wl.y = (apk[p].z & 0xffffu) | (apk[p].w << 16);
      *(uint2*)&sAh[arow[p]][aq[p] * 4] = wh;
      *(uint2*)&sAl[arow[p]][aq[p] * 4] = wl;
    }
#pragma unroll
    for (int p = 0; p < 2; p++) {
      *(uint4*)&sXh[xn[p]][xs[p] * 8] = xh[p];
      *(uint4*)&sXl[xn[p]][xs[p] * 8] = xl[p];
    }
    __syncthreads();
#pragma unroll
    for (int ks = 0; ks < 2; ks++) {
      int koff = ks * 32 + l4 * 8;
      short8 bh[2], bl[2];
#pragma unroll
      for (int ni = 0; ni < 2; ni++) {
        int n = wn * 32 + ni * 16 + l15;
        bh[ni] = *(const short8*)&sXh[n][koff];
        bl[ni] = *(const short8*)&sXl[n][koff];
      }
      short8 ah[4], al[4];
#pragma unroll
      for (int mi = 0; mi < 4; mi++) {
        int row = wm * 64 + mi * 16 + l15;
        ah[mi] = *(const short8*)&sAh[row][koff];
        al[mi] = *(const short8*)&sAl[row][koff];
      }
#pragma unroll
      for (int mi = 0; mi < 4; mi++)
#pragma unroll
        for (int ni = 0; ni < 2; ni++) {
          acc[mi][ni] = __builtin_amdgcn_mfma_f32_16x16x32_bf16(ah[mi], bh[ni], acc[mi][ni], 0, 0, 0);
          acc[mi][ni] = __builtin_amdgcn_mfma_f32_16x16x32_bf16(ah[mi], bl[ni], acc[mi][ni], 0, 0, 0);
          acc[mi][ni] = __builtin_amdgcn_mfma_f32_16x16x32_bf16(al[mi], bh[ni], acc[mi][ni], 0, 0, 0);
        }
    }
    __syncthreads();
  }
  // write partials: C map col=lane&15, row=(lane>>4)*4+r (verified m89/m91)
  float* base = Yp + (size_t)sk * BSZ * NCP;
#pragma unroll
  for (int mi = 0; mi < 4; mi++)
#pragma unroll
    for (int ni = 0; ni < 2; ni++) {
      int row = rbase + wm * 64 + mi * 16 + l4 * 4;
      int col = wn * 32 + ni * 16 + l15;
#pragma unroll
      for (int r = 0; r < 4; r++)
        base[(size_t)(row + r) * NCP + col] = acc[mi][ni][r];
    }
}

// ---- epilogue: sum partials, div, entropy, X+=div, outputs, X split+transpose ----
__global__ __launch_bounds__(256) void k_epilogue2(const float* __restrict__ Yp,
                                                   float* __restrict__ X,
                                                   float* __restrict__ out,
                                                   ushort* __restrict__ Xth,
                                                   ushort* __restrict__ Xtl,
                                                   int tit) {
  __shared__ float xn[16][132];
  int t = threadIdx.x;
  int lane = t & 63, w = t >> 6;
  int r0 = blockIdx.x * 16;
  int c0 = lane << 1;
#pragma unroll
  for (int rr = 0; rr < 4; rr++) {
    int row = r0 + w * 4 + rr;
    float y0 = 0.f, y1 = 0.f;
#pragma unroll
    for (int sk = 0; sk < SKN; sk++) {
      float2 v = *(const float2*)(Yp + (size_t)sk * BSZ * NCP + (size_t)row * NCP + c0);
      y0 += v.x; y1 += v.y;
    }
    float2 xv = *(float2*)(X + (size_t)row * NCP + c0);
    float n0 = xv.x * y0, n1 = xv.y * y1;
    float s = wave_sum(n0 + n1);
    float inv = 1.0f / (s + 1e-8f);
    float d0 = n0 * inv, d1 = n1 * inv;
    float e = -(d0 * logf(d0 + 1e-20f)) - (d1 * logf(d1 + 1e-20f));
    e = wave_sum(e);
    float nx0 = xv.x + d0, nx1 = xv.y + d1;
    xv.x = nx0; xv.y = nx1;
    *(float2*)(X + (size_t)row * NCP + c0) = xv;
    xn[w * 4 + rr][c0] = nx0;
    xn[w * 4 + rr][c0 + 1] = nx1;
    if (c0 < NC)     out[((size_t)row * NC + c0) * TIT + tit] = d0;
    if (c0 + 1 < NC) out[((size_t)row * NC + c0 + 1) * TIT + tit] = d1;
    if (lane == 0)   out[(size_t)BSZ * NC * TIT + (size_t)row * TIT + tit] = e;
  }
  __syncthreads();
  // split+transpose new X rows r0..r0+16 into Xt columns
  int n = t & 127, half = t >> 7;
  ushort hh[8], ll[8];
#pragma unroll
  for (int j = 0; j < 8; j++) {
    float v = xn[half * 8 + j][n];
    ushort hi = f2bf(v);
    hh[j] = hi;
    ll[j] = f2bf(v - bf2f(hi));
  }
  size_t bofs = (size_t)n * BSZ + r0 + half * 8;
  uint4 oh, ol;
  oh.x = (uint)hh[0] | ((uint)hh[1] << 16);
  oh.y = (uint)hh[2] | ((uint)hh[3] << 16);
  oh.z = (uint)hh[4] | ((uint)hh[5] << 16);
  oh.w = (uint)hh[6] | ((uint)hh[7] << 16);
  ol.x = (uint)ll[0] | ((uint)ll[1] << 16);
  ol.y = (uint)ll[2] | ((uint)ll[3] << 16);
  ol.z = (uint)ll[4] | ((uint)ll[5] << 16);
  ol.w = (uint)ll[6] | ((uint)ll[7] << 16);
  *(uint4*)(Xth + bofs) = oh;
  *(uint4*)(Xtl + bofs) = ol;
}

extern "C" void kernel_launch(void* const* d_in, const int* in_sizes, int n_in,
                              void* d_out, int out_size, void* d_ws, size_t ws_size,
                              hipStream_t stream) {
  const float* emb = (const float*)d_in[0];
  const int* lab = (const int*)d_in[1];
  float* out = (float*)d_out;
  float* ws = (float*)d_ws;

  float* ne = ws;                               // region0, dead after syrk
  float* X  = ws;                               // aliases ne (after syrk)
  ushort* Xth = (ushort*)(ws + 524288);
  ushort* Xtl = (ushort*)(ws + 524288 + 262144);
  float* A  = ws + 4194304;                     // fp32, then packed in place
  uint*  Ap = (uint*)A;
  float* Yp = ws + 20971520;
  float* misc = ws + 25165824;
  double* macc = (double*)misc;
  float* meanf = misc + 2;
  int* flag = (int*)(misc + 3);

  k_detect<<<dim3(1), dim3(256), 0, stream>>>(lab, macc, flag);
  k_normalize<<<dim3(BSZ), dim3(256), 0, stream>>>(emb, ne);
  k_syrk<<<dim3(528), dim3(256), 0, stream>>>(ne, A, macc);
  k_meanfin<<<dim3(1), dim3(1), 0, stream>>>(macc, meanf);
  k_split_a<<<dim3(2048), dim3(256), 0, stream>>>(A, meanf);
  k_init_x<<<dim3((BSZ * (NCP / 4) + 255) / 256), dim3(256), 0, stream>>>(lab, flag, X);
  k_splitx0<<<dim3(64), dim3(256), 0, stream>>>(X, Xth, Xtl);
  for (int t = 0; t < TIT; t++) {
    k_gemm<<<dim3(256), dim3(512), 0, stream>>>(Ap, Xth, Xtl, Yp);
    k_epilogue2<<<dim3(256), dim3(256), 0, stream>>>(Yp, X, out, Xth, Xtl, t);
  }
}

// Round 3
// 1677.882 us; speedup vs baseline: 1.5734x; 1.2766x over previous
//
#include <hip/hip_runtime.h>
#include <math.h>

// GTG replicator dynamics. Round 3: both GEMMs on bf16 MFMA (split-bf16,
// 3 products ~ fp32 precision), 32x32x16 fragments, glds-staged swizzled LDS.
//
// ws layout (floats):
//   region0 @ 0 (16.8 MB): nep packed uint [4096][1024] during syrk; afterwards
//     X    [4096][128] f32   @ 0
//     Xth  [128][4096] bf16  @ 524288
//     Xtl  [128][4096] bf16  @ 786432
//   A    [4096][4096] @ 4194304   fp32 from syrk, then packed (hi16|lo16) in place
//   Yp   [skn][4096][128] @ 20971520   (skn = 8 or 16 chosen from ws_size)
//   misc @ 20971520 + skn*524288

#define BSZ  4096
#define DIM  1024
#define NC   100
#define NCP  128
#define NLAB 2048
#define TIT  30

typedef short short8 __attribute__((ext_vector_type(8)));
typedef float f32x16 __attribute__((ext_vector_type(16)));
typedef uint  u32x4  __attribute__((ext_vector_type(4)));

__device__ __forceinline__ float wave_sum(float v) {
#pragma unroll
  for (int off = 32; off > 0; off >>= 1) v += __shfl_xor(v, off, 64);
  return v;
}

__device__ __forceinline__ ushort f2bf(float f) {  // RN float->bf16 bits
  uint u = __float_as_uint(f);
  return (ushort)((u + 0x7fffu + ((u >> 16) & 1u)) >> 16);
}
__device__ __forceinline__ float bf2f(ushort h) {
  return __uint_as_float(((uint)h) << 16);
}
__device__ __forceinline__ uint packsplit(float a) {
  ushort hi = f2bf(a);
  ushort lo = f2bf(a - bf2f(hi));
  return ((uint)hi << 16) | (uint)lo;
}

__device__ __forceinline__ void glds16(const void* g, void* l) {
  __builtin_amdgcn_global_load_lds((const __attribute__((address_space(1))) void*)g,
                                   (__attribute__((address_space(3))) void*)l, 16, 0, 0);
}

// unpack 8 packed uints (2x u32x4) -> hi-frag / lo-frag (8 bf16 each)
__device__ __forceinline__ void unpack8(u32x4 u0, u32x4 u1, short8& h, short8& l) {
  u32x4 hw, lw;
  hw.x = __builtin_amdgcn_perm(u0.y, u0.x, 0x07060302u);
  hw.y = __builtin_amdgcn_perm(u0.w, u0.z, 0x07060302u);
  hw.z = __builtin_amdgcn_perm(u1.y, u1.x, 0x07060302u);
  hw.w = __builtin_amdgcn_perm(u1.w, u1.z, 0x07060302u);
  lw.x = __builtin_amdgcn_perm(u0.y, u0.x, 0x05040100u);
  lw.y = __builtin_amdgcn_perm(u0.w, u0.z, 0x05040100u);
  lw.z = __builtin_amdgcn_perm(u1.y, u1.x, 0x05040100u);
  lw.w = __builtin_amdgcn_perm(u1.w, u1.z, 0x05040100u);
  h = __builtin_bit_cast(short8, hw);
  l = __builtin_bit_cast(short8, lw);
}

// ---- detect label dtype (int32 vs int64 layout) + zero mean acc ----
__global__ void k_detect(const int* __restrict__ lab, double* macc, int* flag) {
  __shared__ int bad;
  if (threadIdx.x == 0) bad = 0;
  __syncthreads();
  int my = 0;
  for (int i = threadIdx.x; i < 1024; i += 256) {
    int lo = lab[2 * i], hi = lab[2 * i + 1];
    if (hi != 0 || lo < 0 || lo >= NC) my = 1;
  }
  if (my) bad = 1;
  __syncthreads();
  if (threadIdx.x == 0) { *macc = 0.0; *flag = (bad ? 0 : 1); }
}

// ---- X0 ----
__global__ void k_init_x(const int* __restrict__ lab, const int* __restrict__ flag,
                         float* __restrict__ X) {
  int gid = blockIdx.x * 256 + threadIdx.x;
  if (gid >= BSZ * (NCP / 4)) return;
  int i = gid >> 5, c4 = (gid & 31) << 2;
  float4 v;
  if (i < NLAB) {
    int l = (*flag) ? lab[2 * i] : lab[i];
    v.x = (c4 + 0 == l) ? 1.f : 0.f;
    v.y = (c4 + 1 == l) ? 1.f : 0.f;
    v.z = (c4 + 2 == l) ? 1.f : 0.f;
    v.w = (c4 + 3 == l) ? 1.f : 0.f;
  } else {
    v.x = (c4 + 0 < NC) ? 0.01f : 0.f;
    v.y = (c4 + 1 < NC) ? 0.01f : 0.f;
    v.z = (c4 + 2 < NC) ? 0.01f : 0.f;
    v.w = (c4 + 3 < NC) ? 0.01f : 0.f;
  }
  *(float4*)(X + (size_t)i * NCP + c4) = v;
}

// ---- row-normalize embedding -> packed split-bf16 ne ----
__global__ __launch_bounds__(256) void k_normalize(const float* __restrict__ emb,
                                                   uint* __restrict__ nep) {
  int row = blockIdx.x, t = threadIdx.x;
  float4 v = ((const float4*)(emb + (size_t)row * DIM))[t];
  float ss = v.x * v.x + v.y * v.y + v.z * v.z + v.w * v.w;
  ss = wave_sum(ss);
  __shared__ float red[4];
  int lane = t & 63, wid = t >> 6;
  if (lane == 0) red[wid] = ss;
  __syncthreads();
  float tot = red[0] + red[1] + red[2] + red[3];
  float sc = 1.0f / (sqrtf(tot) + 1e-12f);
  uint4 o;
  o.x = packsplit(v.x * sc);
  o.y = packsplit(v.y * sc);
  o.z = packsplit(v.z * sc);
  o.w = packsplit(v.w * sc);
  ((uint4*)(nep + (size_t)row * DIM))[t] = o;
}

// ---- A = ne*ne^T via split-bf16 MFMA; clamp[0,1], diag=0, mean acc ----
__global__ __launch_bounds__(256) void k_syrk(const uint* __restrict__ nep,
                                              float* __restrict__ A,
                                              double* __restrict__ macc) {
  int p = blockIdx.x;
  int bi = 0, rem = p;
  while (rem >= 32 - bi) { rem -= 32 - bi; bi++; }
  int bj = bi + rem;
  int rb = bi << 7, cb = bj << 7;

  // panels: [buf][pan(row/col)][128 rows x 32 packed uints], slot=4 uints,
  // slot-XOR swizzle g' = g ^ (row&7)  -> conflict-optimal ds_read_b128
  __shared__ uint sP[2][2][4096];
  __shared__ float red[4];

  int t = threadIdx.x, lane = t & 63, wid = t >> 6;
  int wm = wid >> 1, wn = wid & 1;
  int l31 = lane & 31, lh = lane >> 5;

  f32x16 acc[2][2];
#pragma unroll
  for (int mi = 0; mi < 2; mi++)
#pragma unroll
    for (int ni = 0; ni < 2; ni++)
#pragma unroll
      for (int r = 0; r < 16; r++) acc[mi][ni][r] = 0.f;

#define SYRK_STAGE(BUF, K0) {                                                  \
    int base0 = rb, base1 = cb;                                                \
    _Pragma("unroll")                                                          \
    for (int i = 0; i < 4; i++) {                                              \
      int s = wid * 256 + i * 64 + lane;                                       \
      int row = s >> 3;                                                        \
      int g = (s & 7) ^ (row & 7);                                             \
      glds16(nep + (size_t)(base0 + row) * DIM + (K0) + g * 4,                 \
             &sP[BUF][0][(wid * 256 + i * 64) * 4]);                           \
      glds16(nep + (size_t)(base1 + row) * DIM + (K0) + g * 4,                 \
             &sP[BUF][1][(wid * 256 + i * 64) * 4]);                           \
    }                                                                          \
  }

  SYRK_STAGE(0, 0);
  __syncthreads();
  for (int kt = 0; kt < 32; kt++) {
    int cur = kt & 1;
    if (kt + 1 < 32) SYRK_STAGE(cur ^ 1, (kt + 1) * 32);
#pragma unroll
    for (int ks = 0; ks < 2; ks++) {
      int g0 = ks * 4 + lh * 2;
      short8 ah[2], al[2], bh[2], bl[2];
#pragma unroll
      for (int mi = 0; mi < 2; mi++) {
        int row = wm * 64 + mi * 32 + l31;
        const uint* pb = &sP[cur][0][0];
        u32x4 u0 = *(const u32x4*)(pb + ((row << 3) + (g0 ^ (row & 7))) * 4);
        u32x4 u1 = *(const u32x4*)(pb + ((row << 3) + ((g0 + 1) ^ (row & 7))) * 4);
        unpack8(u0, u1, ah[mi], al[mi]);
      }
#pragma unroll
      for (int ni = 0; ni < 2; ni++) {
        int row = wn * 64 + ni * 32 + l31;
        const uint* pb = &sP[cur][1][0];
        u32x4 u0 = *(const u32x4*)(pb + ((row << 3) + (g0 ^ (row & 7))) * 4);
        u32x4 u1 = *(const u32x4*)(pb + ((row << 3) + ((g0 + 1) ^ (row & 7))) * 4);
        unpack8(u0, u1, bh[ni], bl[ni]);
      }
#pragma unroll
      for (int mi = 0; mi < 2; mi++)
#pragma unroll
        for (int ni = 0; ni < 2; ni++) {
          acc[mi][ni] = __builtin_amdgcn_mfma_f32_32x32x16_bf16(ah[mi], bh[ni], acc[mi][ni], 0, 0, 0);
          acc[mi][ni] = __builtin_amdgcn_mfma_f32_32x32x16_bf16(ah[mi], bl[ni], acc[mi][ni], 0, 0, 0);
          acc[mi][ni] = __builtin_amdgcn_mfma_f32_32x32x16_bf16(al[mi], bh[ni], acc[mi][ni], 0, 0, 0);
        }
    }
    __syncthreads();
  }

  // epilogue: clamp, diag, direct store, mean
  float lsum = 0.f;
#pragma unroll
  for (int mi = 0; mi < 2; mi++)
#pragma unroll
    for (int ni = 0; ni < 2; ni++)
#pragma unroll
      for (int r = 0; r < 16; r++) {
        int gr = rb + wm * 64 + mi * 32 + (r & 3) + 8 * (r >> 2) + 4 * lh;
        int gc = cb + wn * 64 + ni * 32 + l31;
        float v = acc[mi][ni][r];
        v = fminf(fmaxf(v, 0.f), 1.f);
        if (gr == gc) v = 0.f;
        acc[mi][ni][r] = v;
        lsum += v;
        A[(size_t)gr * BSZ + gc] = v;
      }
  if (bi != bj) lsum *= 2.f;
  float bs = wave_sum(lsum);
  if (lane == 0) red[wid] = bs;
  __syncthreads();
  if (t == 0) atomicAdd(macc, (double)(red[0] + red[1] + red[2] + red[3]));

  // transposed store (lower triangle) via LDS transpose, 2 passes of 64 rows
  if (bi != bj) {
    float* tb = (float*)&sP[0][0][0];  // 64x132 f32 = 33.8 KB, reuse staging LDS
#pragma unroll
    for (int ph2 = 0; ph2 < 2; ph2++) {
      __syncthreads();
      if (wm == ph2) {
#pragma unroll
        for (int mi = 0; mi < 2; mi++)
#pragma unroll
          for (int ni = 0; ni < 2; ni++)
#pragma unroll
            for (int r = 0; r < 16; r++) {
              int rl = mi * 32 + (r & 3) + 8 * (r >> 2) + 4 * lh;
              int cl = wn * 64 + ni * 32 + l31;
              tb[rl * 132 + cl] = acc[mi][ni][r];
            }
      }
      __syncthreads();
      int col = t >> 1, rh = (t & 1) * 32;
      float* dst = A + (size_t)(cb + col) * BSZ + rb + ph2 * 64 + rh;
#pragma unroll
      for (int q = 0; q < 8; q++) {
        float4 v4 = make_float4(tb[(rh + q * 4 + 0) * 132 + col],
                                tb[(rh + q * 4 + 1) * 132 + col],
                                tb[(rh + q * 4 + 2) * 132 + col],
                                tb[(rh + q * 4 + 3) * 132 + col]);
        *(float4*)(dst + q * 4) = v4;
      }
    }
  }
}

__global__ void k_meanfin(const double* __restrict__ macc, float* __restrict__ meanf) {
  *meanf = (float)(*macc / (double)((long long)BSZ * BSZ));
}

// ---- threshold + split-bf16 + pack A in place ----
__global__ __launch_bounds__(256) void k_split_a(float* __restrict__ A,
                                                 const float* __restrict__ meanf) {
  float mean = *meanf;
  int b = blockIdx.x, t = threadIdx.x;
#pragma unroll
  for (int i = 0; i < 8; i++) {
    size_t idx = ((size_t)i * 2048 * 256 + (size_t)b * 256 + t);
    float4 v = *(const float4*)(A + idx * 4);
    uint4 o;
    o.x = packsplit((v.x < mean) ? 0.f : v.x);
    o.y = packsplit((v.y < mean) ? 0.f : v.y);
    o.z = packsplit((v.z < mean) ? 0.f : v.z);
    o.w = packsplit((v.w < mean) ? 0.f : v.w);
    *(uint4*)(A + idx * 4) = o;
  }
}

// ---- initial X split+transpose ----
__global__ __launch_bounds__(256) void k_splitx0(const float* __restrict__ X,
                                                 ushort* __restrict__ Xth,
                                                 ushort* __restrict__ Xtl) {
  __shared__ float xk[64][132];
  int t = threadIdx.x;
  int k0 = blockIdx.x * 64;
#pragma unroll
  for (int p = 0; p < 8; p++) {
    int v = p * 256 + t;
    int krow = v >> 5, q = v & 31;
    float4 f = *(const float4*)(X + (size_t)(k0 + krow) * NCP + q * 4);
    *(float4*)&xk[krow][q * 4] = f;
  }
  __syncthreads();
  int n = t >> 1, half = t & 1;
  ushort hh[32], ll[32];
#pragma unroll
  for (int j = 0; j < 32; j++) {
    float v = xk[half * 32 + j][n];
    ushort hi = f2bf(v);
    hh[j] = hi;
    ll[j] = f2bf(v - bf2f(hi));
  }
  size_t base = (size_t)n * BSZ + k0 + half * 32;
#pragma unroll
  for (int g = 0; g < 4; g++) {
    uint4 oh, ol;
    oh.x = (uint)hh[g*8+0] | ((uint)hh[g*8+1] << 16);
    oh.y = (uint)hh[g*8+2] | ((uint)hh[g*8+3] << 16);
    oh.z = (uint)hh[g*8+4] | ((uint)hh[g*8+5] << 16);
    oh.w = (uint)hh[g*8+6] | ((uint)hh[g*8+7] << 16);
    ol.x = (uint)ll[g*8+0] | ((uint)ll[g*8+1] << 16);
    ol.y = (uint)ll[g*8+2] | ((uint)ll[g*8+3] << 16);
    ol.z = (uint)ll[g*8+4] | ((uint)ll[g*8+5] << 16);
    ol.w = (uint)ll[g*8+6] | ((uint)ll[g*8+7] << 16);
    *(uint4*)(Xth + base + g * 8) = oh;
    *(uint4*)(Xtl + base + g * 8) = ol;
  }
}

// ---- MFMA GEMM: Yp[sk] = A_thr[rows, kchunk] @ X[kchunk,:], 3-product split.
// A packed in swizzled LDS (glds); X^T read direct from global (L2-resident),
// 2-deep register pipeline with compile-time phase names. ----
__global__ __launch_bounds__(256) void k_gemm(const uint* __restrict__ Ap,
                                              const ushort* __restrict__ Xth,
                                              const ushort* __restrict__ Xtl,
                                              float* __restrict__ Yp,
                                              int kcw) {
  int b = blockIdx.x;
  int mt = b & 31, sk = b >> 5;
  int rbase = mt << 7;
  int kc0 = sk * kcw;
  int nks = kcw >> 4;

  __shared__ uint sA[2][8192];  // [128 rows][64 uints], 16 slots/row, g^=(row&15)

  int t = threadIdx.x, lane = t & 63, wid = t >> 6;
  int wm = wid >> 1, wn = wid & 1;
  int l31 = lane & 31, lh = lane >> 5;

  f32x16 acc[2][2];
#pragma unroll
  for (int mi = 0; mi < 2; mi++)
#pragma unroll
    for (int ni = 0; ni < 2; ni++)
#pragma unroll
      for (int r = 0; r < 16; r++) acc[mi][ni][r] = 0.f;

#define GEMM_STAGE(BUF, K0) {                                                  \
    _Pragma("unroll")                                                          \
    for (int i = 0; i < 8; i++) {                                              \
      int s = wid * 512 + i * 64 + lane;                                       \
      int row = s >> 4;                                                        \
      int g = (s & 15) ^ (row & 15);                                           \
      glds16(Ap + (size_t)(rbase + row) * BSZ + (K0) + g * 4,                  \
             &sA[BUF][(wid * 512 + i * 64) * 4]);                              \
    }                                                                          \
  }

#define LOADB(KSG, BH, BL) {                                                   \
    int kg = kc0 + (KSG) * 16 + lh * 8;                                        \
    int c0_ = wn * 64 + l31;                                                   \
    BH[0] = *(const short8*)(Xth + (size_t)c0_ * BSZ + kg);                    \
    BL[0] = *(const short8*)(Xtl + (size_t)c0_ * BSZ + kg);                    \
    BH[1] = *(const short8*)(Xth + (size_t)(c0_ + 32) * BSZ + kg);             \
    BL[1] = *(const short8*)(Xtl + (size_t)(c0_ + 32) * BSZ + kg);             \
  }

#define GSTEP(KSG, BHc, BLc, BHn, BLn) {                                       \
    int kt_ = (KSG) >> 2, ks_ = (KSG) & 3, cur_ = kt_ & 1;                     \
    if (ks_ == 0 && (kt_ + 1) * 64 < kcw) GEMM_STAGE(cur_ ^ 1, kc0 + (kt_ + 1) * 64); \
    if ((KSG) + 1 < nks) LOADB((KSG) + 1, BHn, BLn);                           \
    int g0 = ks_ * 4 + lh * 2;                                                 \
    short8 ah[2], al[2];                                                       \
    const uint* pb_ = &sA[cur_][0];                                            \
    _Pragma("unroll")                                                          \
    for (int mi = 0; mi < 2; mi++) {                                           \
      int row = wm * 64 + mi * 32 + l31;                                       \
      u32x4 u0 = *(const u32x4*)(pb_ + ((row << 4) + (g0 ^ (row & 15))) * 4);  \
      u32x4 u1 = *(const u32x4*)(pb_ + ((row << 4) + ((g0 + 1) ^ (row & 15))) * 4); \
      unpack8(u0, u1, ah[mi], al[mi]);                                         \
    }                                                                          \
    _Pragma("unroll")                                                          \
    for (int mi = 0; mi < 2; mi++) {                                           \
      _Pragma("unroll")                                                        \
      for (int ni = 0; ni < 2; ni++) {                                         \
        acc[mi][ni] = __builtin_amdgcn_mfma_f32_32x32x16_bf16(ah[mi], BHc[ni], acc[mi][ni], 0, 0, 0); \
        acc[mi][ni] = __builtin_amdgcn_mfma_f32_32x32x16_bf16(ah[mi], BLc[ni], acc[mi][ni], 0, 0, 0); \
        acc[mi][ni] = __builtin_amdgcn_mfma_f32_32x32x16_bf16(al[mi], BHc[ni], acc[mi][ni], 0, 0, 0); \
      }                                                                        \
    }                                                                          \
    if (ks_ == 3) __syncthreads();                                             \
  }

  short8 bhA[2], blA[2], bhB[2], blB[2];
  GEMM_STAGE(0, kc0);
  LOADB(0, bhA, blA);
  __syncthreads();
  for (int ksg = 0; ksg < nks; ksg += 2) {
    GSTEP(ksg, bhA, blA, bhB, blB);
    GSTEP(ksg + 1, bhB, blB, bhA, blA);
  }

  float* yb = Yp + (size_t)sk * (BSZ * NCP);
#pragma unroll
  for (int mi = 0; mi < 2; mi++)
#pragma unroll
    for (int ni = 0; ni < 2; ni++)
#pragma unroll
      for (int r = 0; r < 16; r++) {
        int row = rbase + wm * 64 + mi * 32 + (r & 3) + 8 * (r >> 2) + 4 * lh;
        int col = wn * 64 + ni * 32 + l31;
        yb[(size_t)row * NCP + col] = acc[mi][ni][r];
      }
}

// ---- epilogue: sum partials, div, entropy, X+=div, outputs, X split+transpose ----
__global__ __launch_bounds__(256) void k_epilogue2(const float* __restrict__ Yp,
                                                   float* __restrict__ X,
                                                   float* __restrict__ out,
                                                   ushort* __restrict__ Xth,
                                                   ushort* __restrict__ Xtl,
                                                   int tit, int skn) {
  __shared__ float xn[16][132];
  int t = threadIdx.x;
  int lane = t & 63, w = t >> 6;
  int r0 = blockIdx.x * 16;
  int c0 = lane << 1;
#pragma unroll
  for (int rr = 0; rr < 4; rr++) {
    int row = r0 + w * 4 + rr;
    float y0 = 0.f, y1 = 0.f;
    for (int sk = 0; sk < skn; sk++) {
      float2 v = *(const float2*)(Yp + (size_t)sk * BSZ * NCP + (size_t)row * NCP + c0);
      y0 += v.x; y1 += v.y;
    }
    float2 xv = *(float2*)(X + (size_t)row * NCP + c0);
    float n0 = xv.x * y0, n1 = xv.y * y1;
    float s = wave_sum(n0 + n1);
    float inv = 1.0f / (s + 1e-8f);
    float d0 = n0 * inv, d1 = n1 * inv;
    float e = -(d0 * logf(d0 + 1e-20f)) - (d1 * logf(d1 + 1e-20f));
    e = wave_sum(e);
    float nx0 = xv.x + d0, nx1 = xv.y + d1;
    xv.x = nx0; xv.y = nx1;
    *(float2*)(X + (size_t)row * NCP + c0) = xv;
    xn[w * 4 + rr][c0] = nx0;
    xn[w * 4 + rr][c0 + 1] = nx1;
    if (c0 < NC)     out[((size_t)row * NC + c0) * TIT + tit] = d0;
    if (c0 + 1 < NC) out[((size_t)row * NC + c0 + 1) * TIT + tit] = d1;
    if (lane == 0)   out[(size_t)BSZ * NC * TIT + (size_t)row * TIT + tit] = e;
  }
  __syncthreads();
  int n = t & 127, half = t >> 7;
  ushort hh[8], ll[8];
#pragma unroll
  for (int j = 0; j < 8; j++) {
    float v = xn[half * 8 + j][n];
    ushort hi = f2bf(v);
    hh[j] = hi;
    ll[j] = f2bf(v - bf2f(hi));
  }
  size_t bofs = (size_t)n * BSZ + r0 + half * 8;
  uint4 oh, ol;
  oh.x = (uint)hh[0] | ((uint)hh[1] << 16);
  oh.y = (uint)hh[2] | ((uint)hh[3] << 16);
  oh.z = (uint)hh[4] | ((uint)hh[5] << 16);
  oh.w = (uint)hh[6] | ((uint)hh[7] << 16);
  ol.x = (uint)ll[0] | ((uint)ll[1] << 16);
  ol.y = (uint)ll[2] | ((uint)ll[3] << 16);
  ol.z = (uint)ll[4] | ((uint)ll[5] << 16);
  ol.w = (uint)ll[6] | ((uint)ll[7] << 16);
  *(uint4*)(Xth + bofs) = oh;
  *(uint4*)(Xtl + bofs) = ol;
}

extern "C" void kernel_launch(void* const* d_in, const int* in_sizes, int n_in,
                              void* d_out, int out_size, void* d_ws, size_t ws_size,
                              hipStream_t stream) {
  const float* emb = (const float*)d_in[0];
  const int* lab = (const int*)d_in[1];
  float* out = (float*)d_out;
  float* ws = (float*)d_ws;

  uint*   nep = (uint*)ws;                       // region0, dead after syrk
  float*  X   = ws;                              // aliases nep (post-syrk)
  ushort* Xth = (ushort*)(ws + 524288);
  ushort* Xtl = (ushort*)(ws + 524288 + 262144);
  float*  A   = ws + 4194304;                    // fp32, then packed in place
  uint*   Ap  = (uint*)A;
  float*  Yp  = ws + 20971520;

  // split-K: 16 if workspace fits the larger partial buffer, else proven 8
  size_t need16 = ((size_t)20971520 + 16 * 524288 + 16) * 4;
  int skn = (ws_size >= need16) ? 16 : 8;
  int kcw = BSZ / skn;

  float* misc = ws + 20971520 + (size_t)skn * 524288;
  double* macc = (double*)misc;
  float* meanf = misc + 2;
  int* flag = (int*)(misc + 3);

  k_detect<<<dim3(1), dim3(256), 0, stream>>>(lab, macc, flag);
  k_normalize<<<dim3(BSZ), dim3(256), 0, stream>>>(emb, nep);
  k_syrk<<<dim3(528), dim3(256), 0, stream>>>(nep, A, macc);
  k_meanfin<<<dim3(1), dim3(1), 0, stream>>>(macc, meanf);
  k_split_a<<<dim3(2048), dim3(256), 0, stream>>>(A, meanf);
  k_init_x<<<dim3((BSZ * (NCP / 4) + 255) / 256), dim3(256), 0, stream>>>(lab, flag, X);
  k_splitx0<<<dim3(64), dim3(256), 0, stream>>>(X, Xth, Xtl);
  for (int t = 0; t < TIT; t++) {
    k_gemm<<<dim3(32 * skn), dim3(256), 0, stream>>>(Ap, Xth, Xtl, Yp, kcw);
    k_epilogue2<<<dim3(256), dim3(256), 0, stream>>>(Yp, X, out, Xth, Xtl, t, skn);
  }
}